// Round 4
// baseline (549.696 us; speedup 1.0000x reference)
//
#include <hip/hip_runtime.h>
#include <hip/hip_bf16.h>

// ModulatedConv (StyleGAN2 conv_transpose2d stride=2, K=3) on gfx950.
// out[b,o,y,x] = inv[b,o] * sum_{i,ky,kx} (scale_w*weight[o,i,ky,kx]) * (s[b,i]*x[b,i,h,w])
// Round 6: counted-vmcnt pipeline (T4). Replace __syncthreads' vmcnt(0)
// drain with the canonical 2-barrier pattern per chunk:
//   A(kc)->regs ; s_barrier ; stage X(kc+1)->LDS[^1] ; s_waitcnt vmcnt(21)
//   (forces own X(kc) writes done, leaves X(kc+1)+A in flight) ; s_barrier ;
//   compute(kc).
// Never vmcnt(0) in the main loop. A single-buffered (JIT, issued first so
// compiler A-waits are >= vmcnt(9) and can't drain the stage) -> fewer VGPR
// -> 3 waves/SIMD (launch_bounds 256,3) -> 12 waves/CU.

typedef __attribute__((ext_vector_type(8))) short short8;
typedef __attribute__((ext_vector_type(4))) float floatx4;

#define CIN   512
#define COUT  512
#define OW    65
#define NSITE 1089     // 33*33 sites (u,v); out y=2u+py, x=2v+px

__device__ __forceinline__ void gload16(const void* g, void* l) {
    __builtin_amdgcn_global_load_lds(
        (const __attribute__((address_space(1))) void*)g,
        (__attribute__((address_space(3))) void*)l, 16, 0, 0);
}

// ---- prep kernels ------------------------------------------------------

// s[b,i] = (1/16) * dot(w[b,:], lin_w[i,:]) + lin_b[i]
__global__ void k_s(const float* __restrict__ w, const float* __restrict__ lin_w,
                    const float* __restrict__ lin_b, float* __restrict__ s)
{
    int i = blockIdx.x * 256 + threadIdx.x;
    int b = blockIdx.y;
    const float* wr = w + b * 512;
    const float* lr = lin_w + (size_t)i * 512;
    float acc = 0.f;
    for (int d = 0; d < 512; d += 4) {
        float4 a = *(const float4*)(wr + d);
        float4 c = *(const float4*)(lr + d);
        acc += a.x*c.x + a.y*c.y + a.z*c.z + a.w*c.w;
    }
    s[b * 512 + i] = acc * 0.0625f + lin_b[i];
}

// fused: q[o,i] = sum_kk weight[o,i,kk]^2 ; wT[t][o][i] = bf16(weight[o,i,t]/48)
__global__ void k_wq(const float* __restrict__ weight,
                     __hip_bfloat16* __restrict__ wT, float* __restrict__ q)
{
    int idx = blockIdx.x * 256 + threadIdx.x;   // o*512+i, < 262144
    const float* p = weight + (size_t)idx * 9;
    float v[9], acc = 0.f;
#pragma unroll
    for (int j = 0; j < 9; ++j) { v[j] = p[j]; acc += v[j] * v[j]; }
    q[idx] = acc;
#pragma unroll
    for (int t = 0; t < 9; ++t)
        wT[t * 262144 + idx] = __float2bfloat16(v[t] * (1.0f / 48.0f));
}

// inv[b,o] = 1/sqrt((1/2304) * sum_i s[b,i]^2 q[o,i] + 1e-8)
__global__ void k_inv(const float* __restrict__ s, const float* __restrict__ q,
                      float* __restrict__ inv)
{
    int idx = blockIdx.x * 256 + threadIdx.x;   // b*512+o
    int b = idx >> 9;
    int o = idx & 511;
    const float* sp = s + b * 512;
    const float* qp = q + (size_t)o * 512;
    float acc = 0.f;
    for (int i = 0; i < 512; i += 4) {
        float4 sv = *(const float4*)(sp + i);
        float4 qv = *(const float4*)(qp + i);
        acc += sv.x*sv.x*qv.x + sv.y*sv.y*qv.y + sv.z*sv.z*qv.z + sv.w*sv.w*qv.w;
    }
    inv[idx] = 1.0f / sqrtf(acc * (1.0f / 2304.0f) + 1e-8f);
}

// zero the halo border of xmp [16][34][34][512]
__global__ void k_zero(__hip_bfloat16* __restrict__ xmp)
{
    int idx = blockIdx.x * 256 + threadIdx.x;   // < 16*132*64
    int kc = idx & 63;
    int j  = (idx >> 6) % 132;
    int b  = (idx >> 6) / 132;
    int r, c;
    if (j < 34)       { r = 0;          c = j; }
    else if (j < 68)  { r = 33;         c = j - 34; }
    else if (j < 100) { r = j - 68 + 1; c = 0; }
    else              { r = j - 100 + 1; c = 33; }
    uint4 z = {0u, 0u, 0u, 0u};
    *(uint4*)(xmp + (((size_t)b * 34 + r) * 34 + c) * 512 + kc * 8) = z;
}

// xmp[b][h+1][w+1][i] = bf16(s[b,i] * x[b,i,h,w])   (channel-minor, padded halo)
__global__ void k_xprep(const float* __restrict__ x, const float* __restrict__ s,
                        __hip_bfloat16* __restrict__ xmp)
{
    __shared__ float tile[32][33];
    int i0 = blockIdx.x * 32;
    int h  = blockIdx.y;
    int b  = blockIdx.z;
    int tw = threadIdx.x & 31;
    int ti = threadIdx.x >> 5;
#pragma unroll
    for (int r = 0; r < 4; ++r) {
        int il = ti + r * 8;
        int i  = i0 + il;
        tile[il][tw] = x[(((size_t)b * 512 + i) * 32 + h) * 32 + tw] * s[b * 512 + i];
    }
    __syncthreads();
#pragma unroll
    for (int r = 0; r < 4; ++r) {
        int wc = ti + r * 8;
        xmp[(((size_t)b * 34 + h + 1) * 34 + (wc + 1)) * 512 + i0 + tw] =
            __float2bfloat16(tile[tw][wc]);
    }
}

// ---- main conv kernel --------------------------------------------------
// Block tile: o=64 x sites=128 x both px parities (py fixed per block).
// 4 waves = 2 wm (o half) x 2 wn (site half); acc[px][a][f] = 64 AGPR.
// Per chunk (counted-vmcnt, never 0 in loop):
//   PREFETCH_A(kc)            (12|6 VMEM -> regs, JIT)
//   s_barrier                 (all waves done READING the parity we overwrite)
//   STAGE_X(kc+1)             (9 gload_lds -> other parity)
//   s_waitcnt vmcnt(21|15)    (own X(kc) writes retired; X(kc+1)+A in flight)
//   s_barrier                 (X(kc) visible from all waves)
//   COMPUTE(kc)               (compiler A-waits are >= vmcnt(9): no drain)

template <int PY> struct PT;
template <> struct PT<0> {
    static constexpr int NT = 6, NG = 4;
    static constexpr int TAPL[6] = {0, 1, 2, 6, 7, 8};
    static constexpr int GTS[4]  = {35, 34, 1, 0};
    static constexpr int GSZ[4]  = {2, 1, 2, 1};
    static constexpr int GST[4]  = {0, 2, 3, 5};
    static constexpr int GPX[6]  = {0, 1, 0, 0, 1, 0};
};
template <> struct PT<1> {
    static constexpr int NT = 3, NG = 2;
    static constexpr int TAPL[3] = {3, 4, 5};
    static constexpr int GTS[2]  = {35, 34};
    static constexpr int GSZ[2]  = {2, 1};
    static constexpr int GST[2]  = {0, 2};
    static constexpr int GPX[3]  = {0, 1, 0};
};

// Macro-expanded pieces: all array indices literal/fully-unrolled (SROA-safe).
#define STAGE_X(NB, K1)                                                    \
    { _Pragma("unroll")                                                    \
      for (int it = 0; it < 4; ++it)                                       \
          gload16(xg[it] + (K1), &Xl[(NB) + it * 2048 + wub]); }

#define PREFETCH_A(K1)                                                     \
    { _Pragma("unroll")                                                    \
      for (int t = 0; t < NT; ++t) {                                       \
          Ar[t][0] = *(const short8*)(wtapP[t] + aoffg[0] + (K1));         \
          Ar[t][1] = *(const short8*)(wtapP[t] + aoffg[1] + (K1));         \
      } }

#define COMPUTE_GROUPS(CB)                                                 \
    { _Pragma("unroll")                                                    \
      for (int g = 0; g < NG; ++g) {                                       \
          short8 B0 = *(const short8*)(&Xl[(CB) + boff[g][0]]);            \
          short8 B1 = *(const short8*)(&Xl[(CB) + boff[g][1]]);            \
          short8 B2 = *(const short8*)(&Xl[(CB) + boff[g][2]]);            \
          short8 B3 = *(const short8*)(&Xl[(CB) + boff[g][3]]);            \
          _Pragma("unroll")                                                \
          for (int j = 0; j < T::GSZ[g]; ++j) {                            \
              const int ti = T::GST[g] + j;                                \
              const int px = T::GPX[ti];                                   \
              acc[px][0][0] = __builtin_amdgcn_mfma_f32_16x16x32_bf16(Ar[ti][0], B0, acc[px][0][0], 0, 0, 0); \
              acc[px][1][0] = __builtin_amdgcn_mfma_f32_16x16x32_bf16(Ar[ti][1], B0, acc[px][1][0], 0, 0, 0); \
              acc[px][0][1] = __builtin_amdgcn_mfma_f32_16x16x32_bf16(Ar[ti][0], B1, acc[px][0][1], 0, 0, 0); \
              acc[px][1][1] = __builtin_amdgcn_mfma_f32_16x16x32_bf16(Ar[ti][1], B1, acc[px][1][1], 0, 0, 0); \
              acc[px][0][2] = __builtin_amdgcn_mfma_f32_16x16x32_bf16(Ar[ti][0], B2, acc[px][0][2], 0, 0, 0); \
              acc[px][1][2] = __builtin_amdgcn_mfma_f32_16x16x32_bf16(Ar[ti][1], B2, acc[px][1][2], 0, 0, 0); \
              acc[px][0][3] = __builtin_amdgcn_mfma_f32_16x16x32_bf16(Ar[ti][0], B3, acc[px][0][3], 0, 0, 0); \
              acc[px][1][3] = __builtin_amdgcn_mfma_f32_16x16x32_bf16(Ar[ti][1], B3, acc[px][1][3], 0, 0, 0); \
          }                                                                \
      } }

// Counted waits (vmcnt retires in order: forcing <=N outstanding guarantees
// everything older than the newest N is done).  Steady: newer-than-X(kc) =
// A(kc) + X(kc+1) = 12+9 (PY0) | 6+9 (PY1).  Tail: A(15) only.
#define WAIT_STEADY                                                        \
    { if constexpr (PY == 0) asm volatile("s_waitcnt vmcnt(21)" ::: "memory"); \
      else                   asm volatile("s_waitcnt vmcnt(15)" ::: "memory"); }
#define WAIT_TAIL                                                          \
    { if constexpr (PY == 0) asm volatile("s_waitcnt vmcnt(12)" ::: "memory"); \
      else                   asm volatile("s_waitcnt vmcnt(6)"  ::: "memory"); }

template <int PY>
__device__ __forceinline__ void conv_body(
    const __hip_bfloat16* __restrict__ wT,
    const __hip_bfloat16* __restrict__ xmp,
    const float* __restrict__ inv,
    float* __restrict__ out,
    short* Xl, const int site_tile, const int o_tile, const int b)
{
    using T = PT<PY>;
    constexpr int NT = T::NT, NG = T::NG;

    const int tid  = threadIdx.x;
    const int lane = tid & 63;
    const int wv   = tid >> 6;
    const int wm   = wv & 1;
    const int wn   = wv >> 1;
    const int quad = lane >> 4;
    const int c16  = lane & 15;

    const int s0     = site_tile * 128;
    const int u_base = s0 / 33;
    const int o_base = o_tile * 64;

    // A fragment global element offsets (within one tap slice, before k0)
    int aoffg[2];
#pragma unroll
    for (int a = 0; a < 2; ++a)
        aoffg[a] = (wm * 32 + a * 16 + c16) * CIN + quad * 8;

    const __hip_bfloat16* wtapP[NT];
#pragma unroll
    for (int t = 0; t < NT; ++t)
        wtapP[t] = wT + ((size_t)(T::TAPL[t] * COUT + o_base)) * CIN;

    // B fragment LDS offsets per (ts-group, f), swizzled
    int boff[NG][4];
#pragma unroll
    for (int f = 0; f < 4; ++f) {
        int site = s0 + wn * 64 + f * 16 + c16;
        int u = site / 33;
        int v = site - u * 33;
        int sb = (u - u_base) * 34 + v;
#pragma unroll
        for (int g = 0; g < NG; ++g) {
            int sl = sb + T::GTS[g];
            boff[g][f] = sl * 32 + ((quad ^ ((sl >> 1) & 3)) << 3);
        }
    }
    // X staging global pointers (hoisted; add k per chunk)
    const __hip_bfloat16* xg[4];
#pragma unroll
    for (int it = 0; it < 4; ++it) {
        int ch   = it * 256 + tid;
        int slot = ch >> 2;
        int kg   = (ch & 3) ^ ((slot >> 1) & 3);
        int r    = slot / 34;
        int c    = slot - r * 34;
        int h1   = u_base + r;                  // padded xmp row (= h_x + 1)
        xg[it] = (slot < 204 && h1 <= 33)
                   ? xmp + (((size_t)b * 34 + h1) * 34 + c) * 512 + kg * 8
                   : xmp;                       // dummy; those slots never read
    }
    // wave-uniform LDS staging base (shorts)
    const int wub = (tid & 192) * 8;

    floatx4 acc[2][2][4];
#pragma unroll
    for (int p = 0; p < 2; ++p)
#pragma unroll
        for (int a = 0; a < 2; ++a)
#pragma unroll
            for (int f = 0; f < 4; ++f)
                acc[p][a][f] = (floatx4){0.f, 0.f, 0.f, 0.f};

    short8 Ar[NT][2];

    // prologue: stage chunk 0 (X -> buf0)
    STAGE_X(0, 0)

#pragma unroll 1
    for (int kc = 0; kc < 16; kc += 2) {
        // even chunk: compute buf0, stage into buf1
        PREFETCH_A(kc * 32)
        __builtin_amdgcn_s_barrier();           // all done reading buf1
        STAGE_X(8192, (kc + 1) * 32)
        WAIT_STEADY                             // own X(kc) retired
        __builtin_amdgcn_s_barrier();           // X(kc) visible block-wide
        COMPUTE_GROUPS(0)

        // odd chunk: compute buf1, stage into buf0 (except last)
        PREFETCH_A((kc + 1) * 32)
        __builtin_amdgcn_s_barrier();           // all done reading buf0
        if (kc < 14) {
            STAGE_X(0, (kc + 2) * 32)
            WAIT_STEADY
        } else {
            WAIT_TAIL
        }
        __builtin_amdgcn_s_barrier();           // X(kc+1) visible block-wide
        COMPUTE_GROUPS(8192)
    }

    // epilogue: D col(lane&15)->site, row(quad*4+reg)->o; both px write the
    // same output line (x = 2v, 2v+1) -> contiguous 128B per (a,f,r) frag row.
#pragma unroll
    for (int a = 0; a < 2; ++a) {
        const int ob = o_base + wm * 32 + a * 16 + quad * 4;
        float iv[4];
#pragma unroll
        for (int r = 0; r < 4; ++r) iv[r] = inv[b * COUT + ob + r];
#pragma unroll
        for (int f = 0; f < 4; ++f) {
            int site = s0 + wn * 64 + f * 16 + c16;
            if (site < NSITE) {
                int u = site / 33;
                int v = site - u * 33;
                int y = 2 * u + PY;
                if (y < OW) {
                    int x0 = 2 * v;
#pragma unroll
                    for (int r = 0; r < 4; ++r) {
                        size_t oi = ((size_t)(b * COUT + ob + r) * OW + y) * OW + x0;
                        out[oi] = acc[0][a][f][r] * iv[r];
                        if (v < 32)
                            out[oi + 1] = acc[1][a][f][r] * iv[r];
                    }
                }
            }
        }
    }
}

__global__ __launch_bounds__(256, 3)
void conv_main(const __hip_bfloat16* __restrict__ wT,
               const __hip_bfloat16* __restrict__ xmp,
               const float* __restrict__ inv,
               float* __restrict__ out)
{
    __shared__ short Xl[16384];   // 32 KB: 2 x (256 slots x 32 k)

    // XCD-chunked swizzle: hw linear id n -> XCD ~ n%8. XCD j gets logical
    // range [j*288,(j+1)*288) = exactly 2 batch slices; within: b outer,
    // o_tile (8), py (2), site (9) inner. Working set per XCD ~ xmp[b]
    // 1.18MB + wT o-slice 0.58MB -> fits 4MB L2.
    const int n  = blockIdx.x + 9 * blockIdx.y + 144 * blockIdx.z;
    const int lg = (n & 7) * 288 + (n >> 3);
    const int b  = lg / 144;
    int rem = lg - b * 144;
    const int o_tile = rem / 18;
    rem -= o_tile * 18;
    const int py   = rem / 9;
    const int site = rem - py * 9;

    if (py == 0) conv_body<0>(wT, xmp, inv, out, Xl, site, o_tile, b);
    else         conv_body<1>(wT, xmp, inv, out, Xl, site, o_tile, b);
}

// ---- launcher ----------------------------------------------------------
extern "C" void kernel_launch(void* const* d_in, const int* in_sizes, int n_in,
                              void* d_out, int out_size, void* d_ws, size_t ws_size,
                              hipStream_t stream)
{
    const float* x      = (const float*)d_in[0];   // (16,512,32,32)
    const float* w      = (const float*)d_in[1];   // (16,512)
    const float* weight = (const float*)d_in[2];   // (1,512,512,3,3)
    const float* lin_w  = (const float*)d_in[3];   // (512,512)
    const float* lin_b  = (const float*)d_in[4];   // (512,)
    float* out = (float*)d_out;                    // (16,512,65,65)

    char* ws = (char*)d_ws;
    float* s_buf   = (float*)(ws);                         //   32 KB
    float* inv_buf = (float*)(ws + 32768);                 //   32 KB
    float* q_buf   = (float*)(ws + 65536);                 //    1 MB
    __hip_bfloat16* wT  = (__hip_bfloat16*)(ws + 1114112); // 4.72 MB [9][512][512]
    __hip_bfloat16* xmp = (__hip_bfloat16*)(ws + 5832704); // 18.9 MB [16][34][34][512]

    k_s    <<<dim3(2, 16),      256, 0, stream>>>(w, lin_w, lin_b, s_buf);
    k_wq   <<<1024,             256, 0, stream>>>(weight, wT, q_buf);
    k_zero <<<528,              256, 0, stream>>>(xmp);
    k_inv  <<<32,               256, 0, stream>>>(s_buf, q_buf, inv_buf);
    k_xprep<<<dim3(16, 32, 16), 256, 0, stream>>>(x, s_buf, xmp);
    conv_main<<<dim3(9, 16, 16), 256, 0, stream>>>(wT, xmp, inv_buf, out);
}

// Round 5
// 398.561 us; speedup vs baseline: 1.3792x; 1.3792x over previous
//
#include <hip/hip_runtime.h>
#include <hip/hip_bf16.h>

// ModulatedConv (StyleGAN2 conv_transpose2d stride=2, K=3) on gfx950.
// out[b,o,y,x] = inv[b,o] * sum_{i,ky,kx} (scale_w*weight[o,i,ky,kx]) * (s[b,i]*x[b,i,h,w])
// Round 7: r3 structure (best so far: A dbuf in regs w/ full-chunk prefetch,
// px-merged blocks, clean 56MB/170MB traffic) with ONLY the sync changed:
// X triple-buffered (3x16KB LDS) + counted s_waitcnt vmcnt(N) -- the wait
// before compute(kc) covers loads issued TWO iterations ago (steady N=44,
// never 0 in the loop), replacing __syncthreads' distance-0 vmcnt(0) drain
// that convoyed every chunk in r0-r3. Raw s_barrier pair per chunk:
// bar#1 = buffer-recycle gate (buf[(kc+2)%3] == buf read by chunk kc-1),
// bar#2 = X(kc) visibility (each wave passed its own counted vmcnt).

typedef __attribute__((ext_vector_type(8))) short short8;
typedef __attribute__((ext_vector_type(4))) float floatx4;

#define CIN   512
#define COUT  512
#define OW    65
#define NSITE 1089     // 33*33 sites (u,v); out y=2u+py, x=2v+px

__device__ __forceinline__ void gload16(const void* g, void* l) {
    __builtin_amdgcn_global_load_lds(
        (const __attribute__((address_space(1))) void*)g,
        (__attribute__((address_space(3))) void*)l, 16, 0, 0);
}

template <int N>
__device__ __forceinline__ void vmwait() {
    asm volatile("s_waitcnt vmcnt(%0)" :: "n"(N) : "memory");
}

// ---- prep kernels ------------------------------------------------------

// s[b,i] = (1/16) * dot(w[b,:], lin_w[i,:]) + lin_b[i]
__global__ void k_s(const float* __restrict__ w, const float* __restrict__ lin_w,
                    const float* __restrict__ lin_b, float* __restrict__ s)
{
    int i = blockIdx.x * 256 + threadIdx.x;
    int b = blockIdx.y;
    const float* wr = w + b * 512;
    const float* lr = lin_w + (size_t)i * 512;
    float acc = 0.f;
    for (int d = 0; d < 512; d += 4) {
        float4 a = *(const float4*)(wr + d);
        float4 c = *(const float4*)(lr + d);
        acc += a.x*c.x + a.y*c.y + a.z*c.z + a.w*c.w;
    }
    s[b * 512 + i] = acc * 0.0625f + lin_b[i];
}

// fused: q[o,i] = sum_kk weight[o,i,kk]^2 ; wT[t][o][i] = bf16(weight[o,i,t]/48)
__global__ void k_wq(const float* __restrict__ weight,
                     __hip_bfloat16* __restrict__ wT, float* __restrict__ q)
{
    int idx = blockIdx.x * 256 + threadIdx.x;   // o*512+i, < 262144
    const float* p = weight + (size_t)idx * 9;
    float v[9], acc = 0.f;
#pragma unroll
    for (int j = 0; j < 9; ++j) { v[j] = p[j]; acc += v[j] * v[j]; }
    q[idx] = acc;
#pragma unroll
    for (int t = 0; t < 9; ++t)
        wT[t * 262144 + idx] = __float2bfloat16(v[t] * (1.0f / 48.0f));
}

// inv[b,o] = 1/sqrt((1/2304) * sum_i s[b,i]^2 q[o,i] + 1e-8)
__global__ void k_inv(const float* __restrict__ s, const float* __restrict__ q,
                      float* __restrict__ inv)
{
    int idx = blockIdx.x * 256 + threadIdx.x;   // b*512+o
    int b = idx >> 9;
    int o = idx & 511;
    const float* sp = s + b * 512;
    const float* qp = q + (size_t)o * 512;
    float acc = 0.f;
    for (int i = 0; i < 512; i += 4) {
        float4 sv = *(const float4*)(sp + i);
        float4 qv = *(const float4*)(qp + i);
        acc += sv.x*sv.x*qv.x + sv.y*sv.y*qv.y + sv.z*sv.z*qv.z + sv.w*sv.w*qv.w;
    }
    inv[idx] = 1.0f / sqrtf(acc * (1.0f / 2304.0f) + 1e-8f);
}

// zero the halo border of xmp [16][34][34][512]
__global__ void k_zero(__hip_bfloat16* __restrict__ xmp)
{
    int idx = blockIdx.x * 256 + threadIdx.x;   // < 16*132*64
    int kc = idx & 63;
    int j  = (idx >> 6) % 132;
    int b  = (idx >> 6) / 132;
    int r, c;
    if (j < 34)       { r = 0;          c = j; }
    else if (j < 68)  { r = 33;         c = j - 34; }
    else if (j < 100) { r = j - 68 + 1; c = 0; }
    else              { r = j - 100 + 1; c = 33; }
    uint4 z = {0u, 0u, 0u, 0u};
    *(uint4*)(xmp + (((size_t)b * 34 + r) * 34 + c) * 512 + kc * 8) = z;
}

// xmp[b][h+1][w+1][i] = bf16(s[b,i] * x[b,i,h,w])   (channel-minor, padded halo)
__global__ void k_xprep(const float* __restrict__ x, const float* __restrict__ s,
                        __hip_bfloat16* __restrict__ xmp)
{
    __shared__ float tile[32][33];
    int i0 = blockIdx.x * 32;
    int h  = blockIdx.y;
    int b  = blockIdx.z;
    int tw = threadIdx.x & 31;
    int ti = threadIdx.x >> 5;
#pragma unroll
    for (int r = 0; r < 4; ++r) {
        int il = ti + r * 8;
        int i  = i0 + il;
        tile[il][tw] = x[(((size_t)b * 512 + i) * 32 + h) * 32 + tw] * s[b * 512 + i];
    }
    __syncthreads();
#pragma unroll
    for (int r = 0; r < 4; ++r) {
        int wc = ti + r * 8;
        xmp[(((size_t)b * 34 + h + 1) * 34 + (wc + 1)) * 512 + i0 + tw] =
            __float2bfloat16(tile[tw][wc]);
    }
}

// ---- main conv kernel --------------------------------------------------
// Block tile: o=64 x sites=128 x both px parities (py fixed per block).
// 4 waves = 2 wm x 2 wn; acc[px][a][f] = 64 AGPR; Ar[2][NT][2] = A dbuf,
// prefetch distance one full chunk. X triple-buffered in LDS.
// Per chunk kc (all indices compile-time):
//   lgkmcnt(0); s_barrier            -- recycle gate for buf[(kc+2)%3]
//   STAGE_X -> buf[(kc+2)%3]         -- 4 gload_lds / wave
//   PREFETCH_A(kc+1) -> Ar[(kc+1)&1] -- 12|6 global loads / wave
//   s_waitcnt vmcnt(VM(kc))          -- X(kc) (2 iters old) retired; newer
//                                       A+X stay in flight (never 0)
//   s_barrier                        -- X(kc) visible block-wide
//   COMPUTE(buf[kc%3], Ar[kc&1])

template <int PY> struct PT;
template <> struct PT<0> {
    static constexpr int NT = 6, NG = 4;
    static constexpr int TAPL[6] = {0, 1, 2, 6, 7, 8};
    static constexpr int GTS[4]  = {35, 34, 1, 0};
    static constexpr int GSZ[4]  = {2, 1, 2, 1};
    static constexpr int GST[4]  = {0, 2, 3, 5};
    static constexpr int GPX[6]  = {0, 1, 0, 0, 1, 0};
    // per-iter issue: stage 4 + A 12.  prologue: X0 4, X1 4, A0 12.
    static constexpr int VM(int kc) {
        return kc == 0 ? 32 : kc <= 13 ? 44 : kc == 14 ? 40 : 24;
    }
};
template <> struct PT<1> {
    static constexpr int NT = 3, NG = 2;
    static constexpr int TAPL[3] = {3, 4, 5};
    static constexpr int GTS[2]  = {35, 34};
    static constexpr int GSZ[2]  = {2, 1};
    static constexpr int GST[2]  = {0, 2};
    static constexpr int GPX[3]  = {0, 1, 0};
    // per-iter issue: stage 4 + A 6.  prologue: X0 4, X1 4, A0 6.
    static constexpr int VM(int kc) {
        return kc == 0 ? 20 : kc <= 13 ? 26 : kc == 14 ? 22 : 12;
    }
};

// Macro-expanded pieces: all array indices literal/fully-unrolled (SROA-safe).
#define STAGE_X(NB, K1)                                                    \
    { _Pragma("unroll")                                                    \
      for (int it = 0; it < 4; ++it)                                       \
          gload16(xg[it] + (K1), &Xl[(NB) + it * 2048 + wub]); }

#define PREFETCH_A(DST, K1)                                                \
    { _Pragma("unroll")                                                    \
      for (int t = 0; t < NT; ++t) {                                       \
          Ar[DST][t][0] = *(const short8*)(wtapP[t] + aoffg[0] + (K1));    \
          Ar[DST][t][1] = *(const short8*)(wtapP[t] + aoffg[1] + (K1));    \
      } }

#define COMPUTE_GROUPS(CB, CUR)                                            \
    { _Pragma("unroll")                                                    \
      for (int g = 0; g < NG; ++g) {                                       \
          short8 B0 = *(const short8*)(&Xl[(CB) + boff[g][0]]);            \
          short8 B1 = *(const short8*)(&Xl[(CB) + boff[g][1]]);            \
          short8 B2 = *(const short8*)(&Xl[(CB) + boff[g][2]]);            \
          short8 B3 = *(const short8*)(&Xl[(CB) + boff[g][3]]);            \
          _Pragma("unroll")                                                \
          for (int j = 0; j < T::GSZ[g]; ++j) {                            \
              const int ti = T::GST[g] + j;                                \
              const int px = T::GPX[ti];                                   \
              acc[px][0][0] = __builtin_amdgcn_mfma_f32_16x16x32_bf16(Ar[CUR][ti][0], B0, acc[px][0][0], 0, 0, 0); \
              acc[px][1][0] = __builtin_amdgcn_mfma_f32_16x16x32_bf16(Ar[CUR][ti][1], B0, acc[px][1][0], 0, 0, 0); \
              acc[px][0][1] = __builtin_amdgcn_mfma_f32_16x16x32_bf16(Ar[CUR][ti][0], B1, acc[px][0][1], 0, 0, 0); \
              acc[px][1][1] = __builtin_amdgcn_mfma_f32_16x16x32_bf16(Ar[CUR][ti][1], B1, acc[px][1][1], 0, 0, 0); \
              acc[px][0][2] = __builtin_amdgcn_mfma_f32_16x16x32_bf16(Ar[CUR][ti][0], B2, acc[px][0][2], 0, 0, 0); \
              acc[px][1][2] = __builtin_amdgcn_mfma_f32_16x16x32_bf16(Ar[CUR][ti][1], B2, acc[px][1][2], 0, 0, 0); \
              acc[px][0][3] = __builtin_amdgcn_mfma_f32_16x16x32_bf16(Ar[CUR][ti][0], B3, acc[px][0][3], 0, 0, 0); \
              acc[px][1][3] = __builtin_amdgcn_mfma_f32_16x16x32_bf16(Ar[CUR][ti][1], B3, acc[px][1][3], 0, 0, 0); \
          }                                                                \
      } }

// One K-chunk, all buffer/parity indices compile-time.  DO_STAGE/DO_A are
// 0/1 literals (dead branches fold).
#define CHUNK(KC, DO_STAGE, DO_A)                                          \
    { asm volatile("s_waitcnt lgkmcnt(0)" ::: "memory");                   \
      __builtin_amdgcn_s_barrier();                                        \
      if (DO_STAGE) STAGE_X((((KC) + 2) % 3) * 8192, ((KC) + 2) * 32)      \
      if (DO_A)     PREFETCH_A(((KC) + 1) & 1, ((KC) + 1) * 32)            \
      vmwait<T::VM(KC)>();                                                 \
      __builtin_amdgcn_s_barrier();                                        \
      COMPUTE_GROUPS(((KC) % 3) * 8192, (KC) & 1) }

template <int PY>
__device__ __forceinline__ void conv_body(
    const __hip_bfloat16* __restrict__ wT,
    const __hip_bfloat16* __restrict__ xmp,
    const float* __restrict__ inv,
    float* __restrict__ out,
    short* Xl, const int site_tile, const int o_tile, const int b)
{
    using T = PT<PY>;
    constexpr int NT = T::NT, NG = T::NG;

    const int tid  = threadIdx.x;
    const int lane = tid & 63;
    const int wv   = tid >> 6;
    const int wm   = wv & 1;
    const int wn   = wv >> 1;
    const int quad = lane >> 4;
    const int c16  = lane & 15;

    const int s0     = site_tile * 128;
    const int u_base = s0 / 33;
    const int o_base = o_tile * 64;

    // A fragment global element offsets (within one tap slice, before k0)
    int aoffg[2];
#pragma unroll
    for (int a = 0; a < 2; ++a)
        aoffg[a] = (wm * 32 + a * 16 + c16) * CIN + quad * 8;

    const __hip_bfloat16* wtapP[NT];
#pragma unroll
    for (int t = 0; t < NT; ++t)
        wtapP[t] = wT + ((size_t)(T::TAPL[t] * COUT + o_base)) * CIN;

    // B fragment LDS offsets per (ts-group, f), swizzled
    int boff[NG][4];
#pragma unroll
    for (int f = 0; f < 4; ++f) {
        int site = s0 + wn * 64 + f * 16 + c16;
        int u = site / 33;
        int v = site - u * 33;
        int sb = (u - u_base) * 34 + v;
#pragma unroll
        for (int g = 0; g < NG; ++g) {
            int sl = sb + T::GTS[g];
            boff[g][f] = sl * 32 + ((quad ^ ((sl >> 1) & 3)) << 3);
        }
    }
    // X staging global pointers (hoisted; add k per chunk)
    const __hip_bfloat16* xg[4];
#pragma unroll
    for (int it = 0; it < 4; ++it) {
        int ch   = it * 256 + tid;
        int slot = ch >> 2;
        int kg   = (ch & 3) ^ ((slot >> 1) & 3);
        int r    = slot / 34;
        int c    = slot - r * 34;
        int h1   = u_base + r;                  // padded xmp row (= h_x + 1)
        xg[it] = (slot < 204 && h1 <= 33)
                   ? xmp + (((size_t)b * 34 + h1) * 34 + c) * 512 + kg * 8
                   : xmp;                       // dummy; those slots never read
    }
    // wave-uniform LDS staging base (shorts)
    const int wub = (tid & 192) * 8;

    floatx4 acc[2][2][4];
#pragma unroll
    for (int p = 0; p < 2; ++p)
#pragma unroll
        for (int a = 0; a < 2; ++a)
#pragma unroll
            for (int f = 0; f < 4; ++f)
                acc[p][a][f] = (floatx4){0.f, 0.f, 0.f, 0.f};

    short8 Ar[2][NT][2];

    // prologue: X(0)->buf0, X(1)->buf1, A(0)->Ar[0]
    STAGE_X(0, 0)
    STAGE_X(8192, 32)
    PREFETCH_A(0, 0)

    CHUNK( 0, 1, 1)  CHUNK( 1, 1, 1)  CHUNK( 2, 1, 1)  CHUNK( 3, 1, 1)
    CHUNK( 4, 1, 1)  CHUNK( 5, 1, 1)  CHUNK( 6, 1, 1)  CHUNK( 7, 1, 1)
    CHUNK( 8, 1, 1)  CHUNK( 9, 1, 1)  CHUNK(10, 1, 1)  CHUNK(11, 1, 1)
    CHUNK(12, 1, 1)  CHUNK(13, 1, 1)  CHUNK(14, 0, 1)  CHUNK(15, 0, 0)

    // epilogue: D col(lane&15)->site, row(quad*4+reg)->o; both px write the
    // same output line (x = 2v, 2v+1) -> contiguous 128B per (a,f,r) frag row.
#pragma unroll
    for (int a = 0; a < 2; ++a) {
        const int ob = o_base + wm * 32 + a * 16 + quad * 4;
        float iv[4];
#pragma unroll
        for (int r = 0; r < 4; ++r) iv[r] = inv[b * COUT + ob + r];
#pragma unroll
        for (int f = 0; f < 4; ++f) {
            int site = s0 + wn * 64 + f * 16 + c16;
            if (site < NSITE) {
                int u = site / 33;
                int v = site - u * 33;
                int y = 2 * u + PY;
                if (y < OW) {
                    int x0 = 2 * v;
#pragma unroll
                    for (int r = 0; r < 4; ++r) {
                        size_t oi = ((size_t)(b * COUT + ob + r) * OW + y) * OW + x0;
                        out[oi] = acc[0][a][f][r] * iv[r];
                        if (v < 32)
                            out[oi + 1] = acc[1][a][f][r] * iv[r];
                    }
                }
            }
        }
    }
}

__global__ __launch_bounds__(256, 2)
void conv_main(const __hip_bfloat16* __restrict__ wT,
               const __hip_bfloat16* __restrict__ xmp,
               const float* __restrict__ inv,
               float* __restrict__ out)
{
    __shared__ short Xl[24576];   // 48 KB: 3 x (256 slots x 32 k)

    // XCD-chunked swizzle: hw linear id n -> XCD ~ n%8. XCD j gets logical
    // range [j*288,(j+1)*288) = exactly 2 batch slices; within: b outer,
    // o_tile (8), py (2), site (9) inner. Working set per XCD ~ xmp[b]
    // 1.18MB + ~3.5 wT o-slices ~2MB -> fits 4MB L2.
    const int n  = blockIdx.x + 9 * blockIdx.y + 144 * blockIdx.z;
    const int lg = (n & 7) * 288 + (n >> 3);
    const int b  = lg / 144;
    int rem = lg - b * 144;
    const int o_tile = rem / 18;
    rem -= o_tile * 18;
    const int py   = rem / 9;
    const int site = rem - py * 9;

    if (py == 0) conv_body<0>(wT, xmp, inv, out, Xl, site, o_tile, b);
    else         conv_body<1>(wT, xmp, inv, out, Xl, site, o_tile, b);
}

// ---- launcher ----------------------------------------------------------
extern "C" void kernel_launch(void* const* d_in, const int* in_sizes, int n_in,
                              void* d_out, int out_size, void* d_ws, size_t ws_size,
                              hipStream_t stream)
{
    const float* x      = (const float*)d_in[0];   // (16,512,32,32)
    const float* w      = (const float*)d_in[1];   // (16,512)
    const float* weight = (const float*)d_in[2];   // (1,512,512,3,3)
    const float* lin_w  = (const float*)d_in[3];   // (512,512)
    const float* lin_b  = (const float*)d_in[4];   // (512,)
    float* out = (float*)d_out;                    // (16,512,65,65)

    char* ws = (char*)d_ws;
    float* s_buf   = (float*)(ws);                         //   32 KB
    float* inv_buf = (float*)(ws + 32768);                 //   32 KB
    float* q_buf   = (float*)(ws + 65536);                 //    1 MB
    __hip_bfloat16* wT  = (__hip_bfloat16*)(ws + 1114112); // 4.72 MB [9][512][512]
    __hip_bfloat16* xmp = (__hip_bfloat16*)(ws + 5832704); // 18.9 MB [16][34][34][512]

    k_s    <<<dim3(2, 16),      256, 0, stream>>>(w, lin_w, lin_b, s_buf);
    k_wq   <<<1024,             256, 0, stream>>>(weight, wT, q_buf);
    k_zero <<<528,              256, 0, stream>>>(xmp);
    k_inv  <<<32,               256, 0, stream>>>(s_buf, q_buf, inv_buf);
    k_xprep<<<dim3(16, 32, 16), 256, 0, stream>>>(x, s_buf, xmp);
    conv_main<<<dim3(9, 16, 16), 256, 0, stream>>>(wT, xmp, inv_buf, out);
}

// Round 6
// 287.809 us; speedup vs baseline: 1.9099x; 1.3848x over previous
//
#include <hip/hip_runtime.h>
#include <hip/hip_bf16.h>

// ModulatedConv (StyleGAN2 conv_transpose2d stride=2, K=3) on gfx950.
// out[b,o,y,x] = inv[b,o] * sum_{i,ky,kx} (scale_w*weight[o,i,ky,kx]) * (s[b,i]*x[b,i,h,w])
// Round 8: address-pattern rework. All rounds 0-5 pinned at ~222us with
// every global load a 16-segment 64B gather (A: 16 rows x 64B; X-stage:
// 16 slots x 64B) -> TA/L2 transaction-pipeline latency-bound. This round:
//  * wTf: weights pre-packed in MFMA-fragment order [tap][o32][kc][a][lane*8]
//    -> each A-load is ONE contiguous 1024B (8 full 128B lines).
//  * xmp2: x pre-packed chunk-major [b][kc][slot][32ch] with the XOR k-slot
//    swizzle baked in -> each stage gload16 reads contiguous 4KB.
//  * k_s / k_inv parallelized 8x (256 blocks, shfl-reduce) - they were 32
//    blocks of 512-deep serial dots (~175us of constant non-conv time).
// Sync structure unchanged from r5 (counted vmcnt, 3-buffer, never 0).

typedef __attribute__((ext_vector_type(8))) short short8;
typedef __attribute__((ext_vector_type(4))) float floatx4;

#define CIN   512
#define COUT  512
#define OW    65
#define NSITE 1089     // 33*33 sites (u,v); out y=2u+py, x=2v+px
#define XSLOT 1312     // 34*34 padded site grid + stage-overrun pad (zeroed)

__device__ __forceinline__ void gload16(const void* g, void* l) {
    __builtin_amdgcn_global_load_lds(
        (const __attribute__((address_space(1))) void*)g,
        (__attribute__((address_space(3))) void*)l, 16, 0, 0);
}

template <int N>
__device__ __forceinline__ void vmwait() {
    asm volatile("s_waitcnt vmcnt(%0)" :: "n"(N) : "memory");
}

// ---- prep kernels ------------------------------------------------------

// s[b,i] = (1/16) * dot(w[b,:], lin_w[i,:]) + lin_b[i]
// grid (16,16), 256 thr = 32 i x 8 k-slices, shfl-reduce over 8 lanes.
__global__ void k_s(const float* __restrict__ w, const float* __restrict__ lin_w,
                    const float* __restrict__ lin_b, float* __restrict__ s)
{
    int li = threadIdx.x >> 3, sl = threadIdx.x & 7;
    int i  = blockIdx.x * 32 + li;
    int b  = blockIdx.y;
    const float* wr = w + b * 512 + sl * 64;
    const float* lr = lin_w + (size_t)i * 512 + sl * 64;
    float acc = 0.f;
#pragma unroll
    for (int d = 0; d < 64; d += 4) {
        float4 a = *(const float4*)(wr + d);
        float4 c = *(const float4*)(lr + d);
        acc += a.x*c.x + a.y*c.y + a.z*c.z + a.w*c.w;
    }
    acc += __shfl_down(acc, 4, 8);
    acc += __shfl_down(acc, 2, 8);
    acc += __shfl_down(acc, 1, 8);
    if (sl == 0) s[b * 512 + i] = acc * 0.0625f + lin_b[i];
}

// fused: q[o,i] = sum_kk weight[o,i,kk]^2 ;
// wTf fragment-major: elem (t,o,i) at
//   ((((t*16+o>>5)*16 + i>>5)*2 + (o>>4)&1)*64 + ((i>>3)&3)*16 + (o&15))*8 + (i&7)
__global__ void k_wq(const float* __restrict__ weight,
                     __hip_bfloat16* __restrict__ wTf, float* __restrict__ q)
{
    int idx = blockIdx.x * 256 + threadIdx.x;   // o*512+i, < 262144
    int o = idx >> 9, i = idx & 511;
    const float* p = weight + (size_t)idx * 9;
    float v[9], acc = 0.f;
#pragma unroll
    for (int j = 0; j < 9; ++j) { v[j] = p[j]; acc += v[j] * v[j]; }
    q[idx] = acc;
    const int o32 = o >> 5, a = (o >> 4) & 1;
    const int kc = i >> 5, quad = (i >> 3) & 3;
    const size_t lanepos = ((size_t)(quad * 16 + (o & 15))) * 8 + (i & 7);
#pragma unroll
    for (int t = 0; t < 9; ++t)
        wTf[(((size_t)(t * 16 + o32) * 16 + kc) * 2 + a) * 512 + lanepos] =
            __float2bfloat16(v[t] * (1.0f / 48.0f));
}

// inv[b,o] = 1/sqrt((1/2304) * sum_i s[b,i]^2 q[o,i] + 1e-8)   (8x parallel)
__global__ void k_inv(const float* __restrict__ s, const float* __restrict__ q,
                      float* __restrict__ inv)
{
    int lo = threadIdx.x >> 3, sl = threadIdx.x & 7;
    int o  = blockIdx.x * 32 + lo;
    int b  = blockIdx.y;
    const float* sp = s + b * 512 + sl * 64;
    const float* qp = q + (size_t)o * 512 + sl * 64;
    float acc = 0.f;
#pragma unroll
    for (int i = 0; i < 64; i += 4) {
        float4 sv = *(const float4*)(sp + i);
        float4 qv = *(const float4*)(qp + i);
        acc += sv.x*sv.x*qv.x + sv.y*sv.y*qv.y + sv.z*sv.z*qv.z + sv.w*sv.w*qv.w;
    }
    acc += __shfl_down(acc, 4, 8);
    acc += __shfl_down(acc, 2, 8);
    acc += __shfl_down(acc, 1, 8);
    if (sl == 0)
        inv[b * 512 + o] = 1.0f / sqrtf(acc * (1.0f / 2304.0f) + 1e-8f);
}

// zero halo (row0,row33,col0,col33) + overrun pad [1156,1312) of xmp2[b][kc]
__global__ void k_zero(__hip_bfloat16* __restrict__ xmp2)
{
    int idx = blockIdx.x * 256 + threadIdx.x;   // < 1152*256 = 294912
    int q4 = idx & 3;
    int t  = idx >> 2;                           // (b*16+kc)*288 + si
    int si = t % 288;
    int bk = t / 288;
    int slot;
    if      (si < 34)  slot = si;
    else if (si < 68)  slot = 33 * 34 + (si - 34);
    else if (si < 100) slot = (si - 68 + 1) * 34;
    else if (si < 132) slot = (si - 100 + 1) * 34 + 33;
    else               slot = 1156 + (si - 132);
    uint4 z = {0u, 0u, 0u, 0u};
    *(uint4*)(xmp2 + ((size_t)bk * XSLOT + slot) * 32 + q4 * 8) = z;
}

// xmp2[b][kc][slot][pos] = bf16(s[b,i]*x[b,i,h,w]) ; slot=(h+1)*34+(w+1),
// pos = ((tw>>3) ^ ((slot>>1)&3))*8 + (tw&7)  (XOR swizzle baked in)
__global__ void k_xprep(const float* __restrict__ x, const float* __restrict__ s,
                        __hip_bfloat16* __restrict__ xmp2)
{
    __shared__ float tile[32][33];
    int kc = blockIdx.x;          // channel tile of 32 == K-chunk
    int h  = blockIdx.y;
    int b  = blockIdx.z;
    int tw = threadIdx.x & 31;
    int ti = threadIdx.x >> 5;
#pragma unroll
    for (int r = 0; r < 4; ++r) {
        int il = ti + r * 8;
        int i  = kc * 32 + il;
        tile[il][tw] = x[(((size_t)b * 512 + i) * 32 + h) * 32 + tw] * s[b * 512 + i];
    }
    __syncthreads();
#pragma unroll
    for (int r = 0; r < 4; ++r) {
        int wc   = ti + r * 8;
        int slot = (h + 1) * 34 + (wc + 1);
        int pos  = (((tw >> 3) ^ ((slot >> 1) & 3)) << 3) | (tw & 7);
        xmp2[((size_t)(b * 16 + kc) * XSLOT + slot) * 32 + pos] =
            __float2bfloat16(tile[tw][wc]);
    }
}

// ---- main conv kernel --------------------------------------------------
// Structure identical to r5 (counted vmcnt, 3 LDS buffers, 2 barriers/chunk)
// but: A-loads = contiguous 1024B fragment reads from wTf; X-stage =
// contiguous 16KB block from xmp2[b][kc]. setprio(1) around MFMA cluster.

template <int PY> struct PT;
template <> struct PT<0> {
    static constexpr int NT = 6, NG = 4;
    static constexpr int TAPL[6] = {0, 1, 2, 6, 7, 8};
    static constexpr int GTS[4]  = {35, 34, 1, 0};
    static constexpr int GSZ[4]  = {2, 1, 2, 1};
    static constexpr int GST[4]  = {0, 2, 3, 5};
    static constexpr int GPX[6]  = {0, 1, 0, 0, 1, 0};
    // per-iter issue: stage 4 + A 12.  prologue: X0 4, X1 4, A0 12.
    static constexpr int VM(int kc) {
        return kc == 0 ? 32 : kc <= 13 ? 44 : kc == 14 ? 40 : 24;
    }
};
template <> struct PT<1> {
    static constexpr int NT = 3, NG = 2;
    static constexpr int TAPL[3] = {3, 4, 5};
    static constexpr int GTS[2]  = {35, 34};
    static constexpr int GSZ[2]  = {2, 1};
    static constexpr int GST[2]  = {0, 2};
    static constexpr int GPX[3]  = {0, 1, 0};
    static constexpr int VM(int kc) {
        return kc == 0 ? 20 : kc <= 13 ? 26 : kc == 14 ? 22 : 12;
    }
};

// Macro-expanded pieces: all array indices literal/fully-unrolled (SROA-safe).
// KCI = K-chunk index (not byte offset).  X kc-stride = XSLOT*32 shorts.
#define STAGE_X(NB, KCI)                                                   \
    { _Pragma("unroll")                                                    \
      for (int it = 0; it < 4; ++it)                                       \
          gload16(xg[it] + (size_t)(KCI) * (XSLOT * 32),                   \
                  &Xl[(NB) + it * 2048 + wub]); }

#define PREFETCH_A(DST, KCI)                                               \
    { _Pragma("unroll")                                                    \
      for (int t = 0; t < NT; ++t) {                                       \
          Ar[DST][t][0] = *(const short8*)(wtapP[t] + (KCI) * 1024);       \
          Ar[DST][t][1] = *(const short8*)(wtapP[t] + (KCI) * 1024 + 512); \
      } }

#define COMPUTE_GROUPS(CB, CUR)                                            \
    { _Pragma("unroll")                                                    \
      for (int g = 0; g < NG; ++g) {                                       \
          short8 B0 = *(const short8*)(&Xl[(CB) + boff[g][0]]);            \
          short8 B1 = *(const short8*)(&Xl[(CB) + boff[g][1]]);            \
          short8 B2 = *(const short8*)(&Xl[(CB) + boff[g][2]]);            \
          short8 B3 = *(const short8*)(&Xl[(CB) + boff[g][3]]);            \
          _Pragma("unroll")                                                \
          for (int j = 0; j < T::GSZ[g]; ++j) {                            \
              const int ti = T::GST[g] + j;                                \
              const int px = T::GPX[ti];                                   \
              acc[px][0][0] = __builtin_amdgcn_mfma_f32_16x16x32_bf16(Ar[CUR][ti][0], B0, acc[px][0][0], 0, 0, 0); \
              acc[px][1][0] = __builtin_amdgcn_mfma_f32_16x16x32_bf16(Ar[CUR][ti][1], B0, acc[px][1][0], 0, 0, 0); \
              acc[px][0][1] = __builtin_amdgcn_mfma_f32_16x16x32_bf16(Ar[CUR][ti][0], B1, acc[px][0][1], 0, 0, 0); \
              acc[px][1][1] = __builtin_amdgcn_mfma_f32_16x16x32_bf16(Ar[CUR][ti][1], B1, acc[px][1][1], 0, 0, 0); \
              acc[px][0][2] = __builtin_amdgcn_mfma_f32_16x16x32_bf16(Ar[CUR][ti][0], B2, acc[px][0][2], 0, 0, 0); \
              acc[px][1][2] = __builtin_amdgcn_mfma_f32_16x16x32_bf16(Ar[CUR][ti][1], B2, acc[px][1][2], 0, 0, 0); \
              acc[px][0][3] = __builtin_amdgcn_mfma_f32_16x16x32_bf16(Ar[CUR][ti][0], B3, acc[px][0][3], 0, 0, 0); \
              acc[px][1][3] = __builtin_amdgcn_mfma_f32_16x16x32_bf16(Ar[CUR][ti][1], B3, acc[px][1][3], 0, 0, 0); \
          }                                                                \
      } }

#define CHUNK(KC, DO_STAGE, DO_A)                                          \
    { asm volatile("s_waitcnt lgkmcnt(0)" ::: "memory");                   \
      __builtin_amdgcn_s_barrier();                                        \
      if (DO_STAGE) STAGE_X((((KC) + 2) % 3) * 8192, (KC) + 2)             \
      if (DO_A)     PREFETCH_A(((KC) + 1) & 1, (KC) + 1)                   \
      vmwait<T::VM(KC)>();                                                 \
      __builtin_amdgcn_s_barrier();                                        \
      __builtin_amdgcn_s_setprio(1);                                       \
      COMPUTE_GROUPS(((KC) % 3) * 8192, (KC) & 1)                          \
      __builtin_amdgcn_s_setprio(0); }

template <int PY>
__device__ __forceinline__ void conv_body(
    const __hip_bfloat16* __restrict__ wTf,
    const __hip_bfloat16* __restrict__ xmp2,
    const float* __restrict__ inv,
    float* __restrict__ out,
    short* Xl, const int site_tile, const int o_tile, const int b)
{
    using T = PT<PY>;
    constexpr int NT = T::NT, NG = T::NG;

    const int tid  = threadIdx.x;
    const int lane = tid & 63;
    const int wv   = tid >> 6;
    const int wm   = wv & 1;
    const int wn   = wv >> 1;
    const int quad = lane >> 4;
    const int c16  = lane & 15;

    const int s0     = site_tile * 128;
    const int u_base = s0 / 33;
    const int o_base = o_tile * 64;
    const int o32    = o_tile * 2 + wm;

    // A fragment base pointers: wTf[t][o32] block, + lane*8 (contiguous/wave)
    const __hip_bfloat16* wtapP[NT];
#pragma unroll
    for (int t = 0; t < NT; ++t)
        wtapP[t] = wTf + (size_t)(T::TAPL[t] * 16 + o32) * 16384 + lane * 8;

    // B fragment LDS offsets per (ts-group, f); XOR swizzle keyed on GLOBAL slot
    int boff[NG][4];
#pragma unroll
    for (int f = 0; f < 4; ++f) {
        int site = s0 + wn * 64 + f * 16 + c16;
        int u = site / 33;
        int v = site - u * 33;
        int sb = (u - u_base) * 34 + v;
#pragma unroll
        for (int g = 0; g < NG; ++g) {
            int sl = sb + T::GTS[g];
            int sg = sl + u_base * 34;
            boff[g][f] = sl * 32 + ((quad ^ ((sg >> 1) & 3)) << 3);
        }
    }
    // X staging: contiguous 16KB block per (b,kc) from slot u_base*34
    const __hip_bfloat16* xb =
        xmp2 + ((size_t)b * 16 * XSLOT + (size_t)u_base * 34) * 32;
    const __hip_bfloat16* xg[4];
#pragma unroll
    for (int it = 0; it < 4; ++it)
        xg[it] = xb + (size_t)(it * 256 + tid) * 8;
    // wave-uniform LDS staging base (shorts)
    const int wub = (tid & 192) * 8;

    floatx4 acc[2][2][4];
#pragma unroll
    for (int p = 0; p < 2; ++p)
#pragma unroll
        for (int a = 0; a < 2; ++a)
#pragma unroll
            for (int f = 0; f < 4; ++f)
                acc[p][a][f] = (floatx4){0.f, 0.f, 0.f, 0.f};

    short8 Ar[2][NT][2];

    // prologue: X(0)->buf0, X(1)->buf1, A(0)->Ar[0]
    STAGE_X(0, 0)
    STAGE_X(8192, 1)
    PREFETCH_A(0, 0)

    CHUNK( 0, 1, 1)  CHUNK( 1, 1, 1)  CHUNK( 2, 1, 1)  CHUNK( 3, 1, 1)
    CHUNK( 4, 1, 1)  CHUNK( 5, 1, 1)  CHUNK( 6, 1, 1)  CHUNK( 7, 1, 1)
    CHUNK( 8, 1, 1)  CHUNK( 9, 1, 1)  CHUNK(10, 1, 1)  CHUNK(11, 1, 1)
    CHUNK(12, 1, 1)  CHUNK(13, 1, 1)  CHUNK(14, 0, 1)  CHUNK(15, 0, 0)

    // epilogue: D col(lane&15)->site, row(quad*4+reg)->o; both px write the
    // same output line (x = 2v, 2v+1) -> contiguous 128B per (a,f,r) frag row.
#pragma unroll
    for (int a = 0; a < 2; ++a) {
        const int ob = o_base + wm * 32 + a * 16 + quad * 4;
        float iv[4];
#pragma unroll
        for (int r = 0; r < 4; ++r) iv[r] = inv[b * COUT + ob + r];
#pragma unroll
        for (int f = 0; f < 4; ++f) {
            int site = s0 + wn * 64 + f * 16 + c16;
            if (site < NSITE) {
                int u = site / 33;
                int v = site - u * 33;
                int y = 2 * u + PY;
                if (y < OW) {
                    int x0 = 2 * v;
#pragma unroll
                    for (int r = 0; r < 4; ++r) {
                        size_t oi = ((size_t)(b * COUT + ob + r) * OW + y) * OW + x0;
                        out[oi] = acc[0][a][f][r] * iv[r];
                        if (v < 32)
                            out[oi + 1] = acc[1][a][f][r] * iv[r];
                    }
                }
            }
        }
    }
}

__global__ __launch_bounds__(256, 2)
void conv_main(const __hip_bfloat16* __restrict__ wTf,
               const __hip_bfloat16* __restrict__ xmp2,
               const float* __restrict__ inv,
               float* __restrict__ out)
{
    __shared__ short Xl[24576];   // 48 KB: 3 x (256 slots x 32 k)

    // XCD-chunked swizzle: hw linear id n -> XCD ~ n%8. XCD j gets logical
    // range [j*288,(j+1)*288) = exactly 2 batch slices; within: b outer,
    // o_tile (8), py (2), site (9) inner.
    const int n  = blockIdx.x + 9 * blockIdx.y + 144 * blockIdx.z;
    const int lg = (n & 7) * 288 + (n >> 3);
    const int b  = lg / 144;
    int rem = lg - b * 144;
    const int o_tile = rem / 18;
    rem -= o_tile * 18;
    const int py   = rem / 9;
    const int site = rem - py * 9;

    if (py == 0) conv_body<0>(wTf, xmp2, inv, out, Xl, site, o_tile, b);
    else         conv_body<1>(wTf, xmp2, inv, out, Xl, site, o_tile, b);
}

// ---- launcher ----------------------------------------------------------
extern "C" void kernel_launch(void* const* d_in, const int* in_sizes, int n_in,
                              void* d_out, int out_size, void* d_ws, size_t ws_size,
                              hipStream_t stream)
{
    const float* x      = (const float*)d_in[0];   // (16,512,32,32)
    const float* w      = (const float*)d_in[1];   // (16,512)
    const float* weight = (const float*)d_in[2];   // (1,512,512,3,3)
    const float* lin_w  = (const float*)d_in[3];   // (512,512)
    const float* lin_b  = (const float*)d_in[4];   // (512,)
    float* out = (float*)d_out;                    // (16,512,65,65)

    char* ws = (char*)d_ws;
    float* s_buf   = (float*)(ws);                          //   32 KB
    float* inv_buf = (float*)(ws + 32768);                  //   32 KB
    float* q_buf   = (float*)(ws + 65536);                  //    1 MB
    __hip_bfloat16* wTf  = (__hip_bfloat16*)(ws + 1114112); // 4.72 MB [9][16][16][2][512]
    __hip_bfloat16* xmp2 = (__hip_bfloat16*)(ws + 5832704); // 21.5 MB [16][16][1312][32]

    k_s    <<<dim3(16, 16),     256, 0, stream>>>(w, lin_w, lin_b, s_buf);
    k_wq   <<<1024,             256, 0, stream>>>(weight, wTf, q_buf);
    k_zero <<<1152,             256, 0, stream>>>(xmp2);
    k_inv  <<<dim3(16, 16),     256, 0, stream>>>(s_buf, q_buf, inv_buf);
    k_xprep<<<dim3(16, 32, 16), 256, 0, stream>>>(x, s_buf, xmp2);
    conv_main<<<dim3(9, 16, 16), 256, 0, stream>>>(wTf, xmp2, inv_buf, out);
}